// Round 3
// baseline (438.040 us; speedup 1.0000x reference)
//
#include <hip/hip_runtime.h>

typedef __bf16 bf16_t;
typedef __bf16 bf16x4 __attribute__((ext_vector_type(4)));
typedef __bf16 bf16x8 __attribute__((ext_vector_type(8)));
typedef float floatx4 __attribute__((ext_vector_type(4)));

#define S_H   (8 * 2048 * 256)   // elements per H buffer (4,194,304)

__device__ inline void split_hl(float v, bf16_t& hi, bf16_t& lo) {
    hi = (bf16_t)v;
    lo = (bf16_t)(v - (float)hi);
}

// ---------------- kernel 0: adj int32 -> bitmask (2048 rows x 64 words) ----------------
__global__ void adjbits_kernel(const int* __restrict__ adj, unsigned* __restrict__ bits) {
    int id = blockIdx.x * 256 + threadIdx.x;   // 131072 words
    const int* p = adj + (size_t)id * 32;
    unsigned w = 0;
#pragma unroll
    for (int j = 0; j < 32; j += 4) {
        int4 v = *(const int4*)(p + j);
        w |= (v.x > 0 ? 1u : 0u) << j;
        w |= (v.y > 0 ? 1u : 0u) << (j + 1);
        w |= (v.z > 0 ? 1u : 0u) << (j + 2);
        w |= (v.w > 0 ? 1u : 0u) << (j + 3);
    }
    bits[id] = w;
}

// ---------------- kernel 1: transpose + hi/lo split W ----------------
__global__ void wtrans_kernel(const float* __restrict__ W1,
                              const float* __restrict__ W2,
                              const float* __restrict__ W3,
                              bf16_t* __restrict__ Wthi, bf16_t* __restrict__ Wtlo) {
    __shared__ float T[64 * 68];
    const int zi = blockIdx.z;
    const float* W = (zi == 0) ? W1 : ((zi == 1) ? W2 : W3);
    bf16_t* ohi = Wthi + zi * 256 * 256;
    bf16_t* olo = Wtlo + zi * 256 * 256;
    const int c0 = blockIdx.x * 64, d0 = blockIdx.y * 64;
    const int tid = threadIdx.x;
#pragma unroll
    for (int i = 0; i < 4; i++) {
        int idx = i * 256 + tid;
        int r = idx >> 4, c4 = (idx & 15) * 4;
        floatx4 v = *(const floatx4*)(W + (c0 + r) * 256 + d0 + c4);
        *(floatx4*)(&T[r * 68 + c4]) = v;
    }
    __syncthreads();
#pragma unroll
    for (int i = 0; i < 4; i++) {
        int idx = i * 256 + tid;
        int rd = idx & 63, cc4 = (idx >> 6) * 4;
        bf16x4 vh, vl;
#pragma unroll
        for (int ii = 0; ii < 4; ii++) {
            float v = T[(cc4 + ii) * 68 + rd];
            bf16_t h, l; split_hl(v, h, l);
            vh[ii] = h; vl[ii] = l;
        }
        *(bf16x4*)(ohi + (d0 + rd) * 256 + c0 + cc4) = vh;
        *(bf16x4*)(olo + (d0 + rd) * 256 + c0 + cc4) = vl;
    }
}

// ---------------- kernel 2: projections (X fp32, W hi/lo bf16) ----------------
__global__ __launch_bounds__(256) void proj_kernel(
    const float* __restrict__ X,
    const bf16_t* __restrict__ Wthi, const bf16_t* __restrict__ Wtlo,
    bf16_t* __restrict__ H1hi, bf16_t* __restrict__ H1lo,
    bf16_t* __restrict__ H2hi, bf16_t* __restrict__ H2lo,
    bf16_t* __restrict__ H3t) {
    __shared__ bf16_t Xh[64 * 40], Xl[64 * 40];
    __shared__ bf16_t Wh[256 * 40], Wl[256 * 40];
    const int z = blockIdx.y;
    const int row0 = blockIdx.x * 64;
    const int tid = threadIdx.x;
    const int w = tid >> 6, lane = tid & 63;
    const int m = lane & 15, q = lane >> 4;
    const bf16_t* Wzh = Wthi + z * 256 * 256;
    const bf16_t* Wzl = Wtlo + z * 256 * 256;

    floatx4 acc[16];
#pragma unroll
    for (int i = 0; i < 16; i++) acc[i] = (floatx4){0.f, 0.f, 0.f, 0.f};

    for (int c0 = 0; c0 < 256; c0 += 32) {
#pragma unroll
        for (int i = 0; i < 2; i++) {
            int idx = i * 256 + tid;
            int r = idx >> 3, c4 = (idx & 7) * 4;
            floatx4 v = *(const floatx4*)(X + (size_t)(row0 + r) * 256 + c0 + c4);
            bf16x4 vh, vl;
#pragma unroll
            for (int ii = 0; ii < 4; ii++) {
                bf16_t h, l; split_hl(v[ii], h, l);
                vh[ii] = h; vl[ii] = l;
            }
            *(bf16x4*)(&Xh[r * 40 + c4]) = vh;
            *(bf16x4*)(&Xl[r * 40 + c4]) = vl;
        }
#pragma unroll
        for (int i = 0; i < 4; i++) {
            int idx = i * 256 + tid;
            int d = idx >> 2, c8 = (idx & 3) * 8;
            *(bf16x8*)(&Wh[d * 40 + c8]) = *(const bf16x8*)(Wzh + d * 256 + c0 + c8);
            *(bf16x8*)(&Wl[d * 40 + c8]) = *(const bf16x8*)(Wzl + d * 256 + c0 + c8);
        }
        __syncthreads();
        bf16x8 ah = *(const bf16x8*)(&Xh[(w * 16 + m) * 40 + q * 8]);
        bf16x8 al = *(const bf16x8*)(&Xl[(w * 16 + m) * 40 + q * 8]);
#pragma unroll
        for (int nt = 0; nt < 16; nt++) {
            bf16x8 bh = *(const bf16x8*)(&Wh[(nt * 16 + m) * 40 + q * 8]);
            bf16x8 bl = *(const bf16x8*)(&Wl[(nt * 16 + m) * 40 + q * 8]);
            acc[nt] = __builtin_amdgcn_mfma_f32_16x16x32_bf16(ah, bh, acc[nt], 0, 0, 0);
            acc[nt] = __builtin_amdgcn_mfma_f32_16x16x32_bf16(ah, bl, acc[nt], 0, 0, 0);
            acc[nt] = __builtin_amdgcn_mfma_f32_16x16x32_bf16(al, bh, acc[nt], 0, 0, 0);
        }
        __syncthreads();
    }
    const int rbase = row0 + w * 16 + q * 4;
    if (z < 2) {
        bf16_t* Hhi = (z == 0) ? H1hi : H2hi;
        bf16_t* Hlo = (z == 0) ? H1lo : H2lo;
#pragma unroll
        for (int nt = 0; nt < 16; nt++)
#pragma unroll
            for (int r = 0; r < 4; r++) {
                bf16_t h, l; split_hl(acc[nt][r], h, l);
                int off = (rbase + r) * 256 + nt * 16 + m;
                Hhi[off] = h;
                Hlo[off] = l;
            }
    } else {
#pragma unroll
        for (int nt = 0; nt < 16; nt++)
#pragma unroll
            for (int r = 0; r < 4; r++) {
                int token = rbase + r;
                int b = token >> 11, n = token & 2047;
                H3t[(size_t)(b * 256 + nt * 16 + m) * 2048 + n] = (bf16_t)acc[nt][r];
            }
    }
}

// ---------------- kernel 3: flash attention ----------------
// 256 threads = 4 waves = 64 queries per block; grid (32,8,2) = 512 blocks.
// Register budget (~120 arch + ~68 acc ≈ 188/wave) caps the CU at 8 waves: two
// INDEPENDENT 4-wave blocks co-reside (2x53KB LDS <= 160KB), so one block computes
// while the other sits at its barrier (round-2 lesson: occupancy can't rise, so
// overlap must come from independent barrier domains).
// LDS tiles are linear + XOR-swizzled so every bf16x8 access is a true aligned
// ds_read_b128 with uniform bank load (old 260/40-strides were 16B-misaligned ->
// split reads + 4-8 way conflicts, 7.6M conflict cycles).
#define KSW(row, byteoff) ((byteoff) ^ (((row) & 7) << 4))     // Kl: row stride 512B
#define VSW(row, byteoff) ((byteoff) ^ ((((row) >> 1) & 3) << 4)) // Vl/Pl: row stride 64B
__global__ __launch_bounds__(256, 2) void attn_kernel(
    const bf16_t* __restrict__ H1hi, const bf16_t* __restrict__ H1lo,
    const bf16_t* __restrict__ H2hi, const bf16_t* __restrict__ H2lo,
    const bf16_t* __restrict__ H3t, const unsigned* __restrict__ adjbits,
    float* __restrict__ Opart, float* __restrict__ mpart, float* __restrict__ lpart,
    int klen) {
    __shared__ bf16_t Kl[2][32 * 256];   // hi/lo K tile, swizzled
    __shared__ bf16_t Vl[256 * 32];      // Vt tile, swizzled
    __shared__ bf16_t Pl[4][16 * 32];    // per-wave P round-trip, swizzled

    const int b = blockIdx.y;
    const int q0 = blockIdx.x * 64;
    const int kz = blockIdx.z;
    const int tid = threadIdx.x;
    const int w = tid >> 6, lane = tid & 63;
    const int m = lane & 15, q = lane >> 4;

    char* KlB = (char*)&Kl[0][0];
    char* KlB2 = (char*)&Kl[1][0];
    char* VlB = (char*)&Vl[0];
    char* PlB = (char*)&Pl[w][0];

    // Q fragments (A-layout: row = lane&15), hi+lo split, K=256 -> 8 chunks
    const bf16_t* qrh = H1hi + (size_t)(b * 2048 + q0 + w * 16 + m) * 256;
    const bf16_t* qrl = H1lo + (size_t)(b * 2048 + q0 + w * 16 + m) * 256;
    bf16x8 qhi[8], qlo[8];
#pragma unroll
    for (int ck = 0; ck < 8; ck++) {
        qhi[ck] = *(const bf16x8*)(qrh + ck * 32 + q * 8);
        qlo[ck] = *(const bf16x8*)(qrl + ck * 32 + q * 8);
    }

    bf16x8 vones;
#pragma unroll
    for (int i = 0; i < 8; i++) vones[i] = (bf16_t)1.0f;

    float m_run[4];
#pragma unroll
    for (int r = 0; r < 4; r++) m_run[r] = -3.0e38f;
    floatx4 l_acc = (floatx4){0.f, 0.f, 0.f, 0.f};
    floatx4 o[16];
#pragma unroll
    for (int i = 0; i < 16; i++) o[i] = (floatx4){0.f, 0.f, 0.f, 0.f};

    const unsigned* bitrow[4];
#pragma unroll
    for (int r = 0; r < 4; r++)
        bitrow[r] = adjbits + (size_t)(q0 + w * 16 + q * 4 + r) * 64;

    // staging: 1024 chunks of K (hi+lo) and 1024 of V across 256 threads -> 4 each
    bf16x8 rkh[4], rkl[4], rvv[4];
    const int kbeg = kz * klen, kend = kbeg + klen;

#pragma unroll
    for (int i = 0; i < 4; i++) {   // prefetch first tile
        int ci = i * 256 + tid;
        int kr = ci >> 5, c8 = (ci & 31) * 8;
        rkh[i] = *(const bf16x8*)(H2hi + (size_t)(b * 2048 + kbeg + kr) * 256 + c8);
        rkl[i] = *(const bf16x8*)(H2lo + (size_t)(b * 2048 + kbeg + kr) * 256 + c8);
        int d = ci >> 2, k8 = (ci & 3) * 8;
        rvv[i] = *(const bf16x8*)(H3t + (size_t)(b * 256 + d) * 2048 + kbeg + k8);
    }

    for (int k0 = kbeg; k0 < kend; k0 += 32) {
        __syncthreads();   // prior iter's LDS readers done
#pragma unroll
        for (int i = 0; i < 4; i++) {
            int ci = i * 256 + tid;
            int kr = ci >> 5, cb = (ci & 31) * 16;          // byte col
            *(bf16x8*)(KlB  + KSW(kr, kr * 512 + cb)) = rkh[i];
            *(bf16x8*)(KlB2 + KSW(kr, kr * 512 + cb)) = rkl[i];
            int d = ci >> 2, kb = (ci & 3) * 16;            // byte col
            *(bf16x8*)(VlB + VSW(d, d * 64 + kb)) = rvv[i];
        }
        __syncthreads();
        if (k0 + 32 < kend) {   // prefetch next tile while computing
            int kn = k0 + 32;
#pragma unroll
            for (int i = 0; i < 4; i++) {
                int ci = i * 256 + tid;
                int kr = ci >> 5, c8 = (ci & 31) * 8;
                rkh[i] = *(const bf16x8*)(H2hi + (size_t)(b * 2048 + kn + kr) * 256 + c8);
                rkl[i] = *(const bf16x8*)(H2lo + (size_t)(b * 2048 + kn + kr) * 256 + c8);
                int d = ci >> 2, k8 = (ci & 3) * 8;
                rvv[i] = *(const bf16x8*)(H3t + (size_t)(b * 256 + d) * 2048 + kn + k8);
            }
        }

        // ---- S = Q K^T (hi*hi + hi*lo + lo*hi), 16 rows x 32 keys per wave ----
        floatx4 s[2];
#pragma unroll
        for (int t = 0; t < 2; t++) {
            floatx4 accs = (floatx4){0.f, 0.f, 0.f, 0.f};
            const int row = t * 16 + m;
#pragma unroll
            for (int ck = 0; ck < 8; ck++) {
                const int cb = ck * 64 + q * 16;   // byte col
                bf16x8 khi = *(const bf16x8*)(KlB  + KSW(row, row * 512 + cb));
                bf16x8 klo = *(const bf16x8*)(KlB2 + KSW(row, row * 512 + cb));
                accs = __builtin_amdgcn_mfma_f32_16x16x32_bf16(qhi[ck], khi, accs, 0, 0, 0);
                accs = __builtin_amdgcn_mfma_f32_16x16x32_bf16(qhi[ck], klo, accs, 0, 0, 0);
                accs = __builtin_amdgcn_mfma_f32_16x16x32_bf16(qlo[ck], khi, accs, 0, 0, 0);
            }
            s[t] = accs;
        }

        // ---- leaky-relu + mask + tile row max ----
        unsigned aw[4];
#pragma unroll
        for (int r = 0; r < 4; r++) aw[r] = bitrow[r][k0 >> 5];
        float p[2][4], tmax[4];
#pragma unroll
        for (int r = 0; r < 4; r++) tmax[r] = -3.0e38f;
#pragma unroll
        for (int t = 0; t < 2; t++)
#pragma unroll
            for (int r = 0; r < 4; r++) {
                float v = s[t][r];
                v = (v > 0.f) ? v : 0.2f * v;
                v = ((aw[r] >> (t * 16 + m)) & 1u) ? v : -1.0e12f;
                p[t][r] = v;
                tmax[r] = fmaxf(tmax[r], v);
            }
#pragma unroll
        for (int off = 1; off < 16; off <<= 1)
#pragma unroll
            for (int r = 0; r < 4; r++)
                tmax[r] = fmaxf(tmax[r], __shfl_xor(tmax[r], off, 64));

        // ---- online softmax update (skip rescale when max didn't rise) ----
        int rise = 0;
        float mnew[4];
#pragma unroll
        for (int r = 0; r < 4; r++) {
            mnew[r] = fmaxf(m_run[r], tmax[r]);
            rise |= (mnew[r] > m_run[r]);
        }
        if (__any(rise)) {
#pragma unroll
            for (int r = 0; r < 4; r++) {
                float alpha = __expf(m_run[r] - mnew[r]);
                m_run[r] = mnew[r];
                l_acc[r] *= alpha;
#pragma unroll
                for (int nt = 0; nt < 16; nt++) o[nt][r] *= alpha;
            }
        }
#pragma unroll
        for (int t = 0; t < 2; t++)
#pragma unroll
            for (int r = 0; r < 4; r++)
                p[t][r] = __expf(p[t][r] - m_run[r]);

        // ---- P: C-layout -> per-wave LDS -> A-layout (no barrier; same wave) ----
#pragma unroll
        for (int t = 0; t < 2; t++)
#pragma unroll
            for (int r = 0; r < 4; r++) {
                int row = q * 4 + r;
                *(bf16_t*)(PlB + VSW(row, row * 64 + (t * 16 + m) * 2)) = (bf16_t)p[t][r];
            }
        bf16x8 pf = *(const bf16x8*)(PlB + VSW(m, m * 64 + q * 16));

        // ---- l += P @ ones (denominator as a 17th output column) ----
        l_acc = __builtin_amdgcn_mfma_f32_16x16x32_bf16(pf, vones, l_acc, 0, 0, 0);

        // ---- O += P @ V ----
#pragma unroll
        for (int nt = 0; nt < 16; nt++) {
            const int vr = nt * 16 + m;
            bf16x8 vf = *(const bf16x8*)(VlB + VSW(vr, vr * 64 + q * 16));
            o[nt] = __builtin_amdgcn_mfma_f32_16x16x32_bf16(pf, vf, o[nt], 0, 0, 0);
        }
    }

    // ---- epilogue: write unnormalized partials + per-row (m,l) ----
    const int rowg = kz * 16384 + b * 2048 + q0 + w * 16 + q * 4;
#pragma unroll
    for (int nt = 0; nt < 16; nt++)
#pragma unroll
        for (int r = 0; r < 4; r++)
            Opart[(size_t)(rowg + r) * 256 + nt * 16 + m] = o[nt][r];
    if (m == 0) {
#pragma unroll
        for (int r = 0; r < 4; r++) {
            mpart[rowg + r] = m_run[r];
            lpart[rowg + r] = l_acc[r];
        }
    }
}

// ---------------- kernel 4: merge splits + normalize + relu ----------------
__global__ __launch_bounds__(256) void merge_kernel(
    const float* __restrict__ Opart, const float* __restrict__ mpart,
    const float* __restrict__ lpart, float* __restrict__ out, int S) {
    int gid = blockIdx.x * 256 + threadIdx.x;
    int row = gid >> 6, c4 = (gid & 63) * 4;
    float M = -3.0e38f;
    for (int s = 0; s < S; s++) M = fmaxf(M, mpart[s * 16384 + row]);
    float denom = 0.f;
    float4 acc = make_float4(0.f, 0.f, 0.f, 0.f);
    for (int s = 0; s < S; s++) {
        float sc = __expf(mpart[s * 16384 + row] - M);
        denom += lpart[s * 16384 + row] * sc;
        float4 v = *(const float4*)(Opart + ((size_t)(s * 16384 + row)) * 256 + c4);
        acc.x += v.x * sc; acc.y += v.y * sc; acc.z += v.z * sc; acc.w += v.w * sc;
    }
    float inv = 1.f / denom;
    float4 r;
    r.x = fmaxf(acc.x * inv, 0.f);
    r.y = fmaxf(acc.y * inv, 0.f);
    r.z = fmaxf(acc.z * inv, 0.f);
    r.w = fmaxf(acc.w * inv, 0.f);
    *(float4*)(out + (size_t)row * 256 + c4) = r;
}

extern "C" void kernel_launch(void* const* d_in, const int* in_sizes, int n_in,
                              void* d_out, int out_size, void* d_ws, size_t ws_size,
                              hipStream_t stream) {
    const float* X   = (const float*)d_in[0];
    const int*   adj = (const int*)d_in[1];
    const float* W1  = (const float*)d_in[2];
    const float* W2  = (const float*)d_in[3];
    const float* W3  = (const float*)d_in[4];
    float* out = (float*)d_out;

    char* ws = (char*)d_ws;
    bf16_t* H1hi = (bf16_t*)(ws + (size_t)0 * S_H * 2);
    bf16_t* H1lo = (bf16_t*)(ws + (size_t)1 * S_H * 2);
    bf16_t* H2hi = (bf16_t*)(ws + (size_t)2 * S_H * 2);
    bf16_t* H2lo = (bf16_t*)(ws + (size_t)3 * S_H * 2);
    bf16_t* H3t  = (bf16_t*)(ws + (size_t)4 * S_H * 2);
    size_t off = (size_t)5 * S_H * 2;                    // 41,943,040
    bf16_t* Wthi = (bf16_t*)(ws + off);                  // 393,216 B
    bf16_t* Wtlo = (bf16_t*)(ws + off + 393216);         // 393,216 B
    float* mpart = (float*)(ws + off);                   // overlays Wt (dead after proj)
    float* lpart = (float*)(ws + off + 262144);
    unsigned* adjb = (unsigned*)(ws + off + 786432);     // 524,288 B
    size_t opart_off = off + 786432 + 524288;
    const size_t need2 = opart_off + (size_t)2 * 16384 * 256 * 4;  // ~76.8 MB

    int S = (ws_size >= need2) ? 2 : 1;
    float* Opart = (S > 1) ? (float*)(ws + opart_off) : out;

    adjbits_kernel<<<512, 256, 0, stream>>>(adj, adjb);
    wtrans_kernel<<<dim3(4, 4, 3), 256, 0, stream>>>(W1, W2, W3, Wthi, Wtlo);
    proj_kernel<<<dim3(256, 3), 256, 0, stream>>>(X, Wthi, Wtlo,
                                                  H1hi, H1lo, H2hi, H2lo, H3t);
    attn_kernel<<<dim3(32, 8, S), 256, 0, stream>>>(H1hi, H1lo, H2hi, H2lo, H3t,
                                                    adjb, Opart, mpart, lpart, 2048 / S);
    merge_kernel<<<4096, 256, 0, stream>>>(Opart, mpart, lpart, out, S);
}

// Round 4
// 244.889 us; speedup vs baseline: 1.7887x; 1.7887x over previous
//
#include <hip/hip_runtime.h>

typedef __bf16 bf16_t;
typedef __bf16 bf16x4 __attribute__((ext_vector_type(4)));
typedef __bf16 bf16x8 __attribute__((ext_vector_type(8)));
typedef float floatx4 __attribute__((ext_vector_type(4)));

#define S_H   (8 * 2048 * 256)   // elements per H buffer (4,194,304)

__device__ inline void split_hl(float v, bf16_t& hi, bf16_t& lo) {
    hi = (bf16_t)v;
    lo = (bf16_t)(v - (float)hi);
}

// ---------------- kernel 0: adj int32 -> bitmask (2048 rows x 64 words) ----------------
__global__ void adjbits_kernel(const int* __restrict__ adj, unsigned* __restrict__ bits) {
    int id = blockIdx.x * 256 + threadIdx.x;   // 131072 words
    const int* p = adj + (size_t)id * 32;
    unsigned w = 0;
#pragma unroll
    for (int j = 0; j < 32; j += 4) {
        int4 v = *(const int4*)(p + j);
        w |= (v.x > 0 ? 1u : 0u) << j;
        w |= (v.y > 0 ? 1u : 0u) << (j + 1);
        w |= (v.z > 0 ? 1u : 0u) << (j + 2);
        w |= (v.w > 0 ? 1u : 0u) << (j + 3);
    }
    bits[id] = w;
}

// ---------------- kernel 1: transpose + hi/lo split W ----------------
__global__ void wtrans_kernel(const float* __restrict__ W1,
                              const float* __restrict__ W2,
                              const float* __restrict__ W3,
                              bf16_t* __restrict__ Wthi, bf16_t* __restrict__ Wtlo) {
    __shared__ float T[64 * 68];
    const int zi = blockIdx.z;
    const float* W = (zi == 0) ? W1 : ((zi == 1) ? W2 : W3);
    bf16_t* ohi = Wthi + zi * 256 * 256;
    bf16_t* olo = Wtlo + zi * 256 * 256;
    const int c0 = blockIdx.x * 64, d0 = blockIdx.y * 64;
    const int tid = threadIdx.x;
#pragma unroll
    for (int i = 0; i < 4; i++) {
        int idx = i * 256 + tid;
        int r = idx >> 4, c4 = (idx & 15) * 4;
        floatx4 v = *(const floatx4*)(W + (c0 + r) * 256 + d0 + c4);
        *(floatx4*)(&T[r * 68 + c4]) = v;
    }
    __syncthreads();
#pragma unroll
    for (int i = 0; i < 4; i++) {
        int idx = i * 256 + tid;
        int rd = idx & 63, cc4 = (idx >> 6) * 4;
        bf16x4 vh, vl;
#pragma unroll
        for (int ii = 0; ii < 4; ii++) {
            float v = T[(cc4 + ii) * 68 + rd];
            bf16_t h, l; split_hl(v, h, l);
            vh[ii] = h; vl[ii] = l;
        }
        *(bf16x4*)(ohi + (d0 + rd) * 256 + c0 + cc4) = vh;
        *(bf16x4*)(olo + (d0 + rd) * 256 + c0 + cc4) = vl;
    }
}

// ---------------- kernel 2: projections (X fp32, W hi/lo bf16) ----------------
__global__ __launch_bounds__(256) void proj_kernel(
    const float* __restrict__ X,
    const bf16_t* __restrict__ Wthi, const bf16_t* __restrict__ Wtlo,
    bf16_t* __restrict__ H1hi, bf16_t* __restrict__ H1lo,
    bf16_t* __restrict__ H2hi, bf16_t* __restrict__ H2lo,
    bf16_t* __restrict__ H3t) {
    __shared__ bf16_t Xh[64 * 40], Xl[64 * 40];
    __shared__ bf16_t Wh[256 * 40], Wl[256 * 40];
    const int z = blockIdx.y;
    const int row0 = blockIdx.x * 64;
    const int tid = threadIdx.x;
    const int w = tid >> 6, lane = tid & 63;
    const int m = lane & 15, q = lane >> 4;
    const bf16_t* Wzh = Wthi + z * 256 * 256;
    const bf16_t* Wzl = Wtlo + z * 256 * 256;

    floatx4 acc[16];
#pragma unroll
    for (int i = 0; i < 16; i++) acc[i] = (floatx4){0.f, 0.f, 0.f, 0.f};

    for (int c0 = 0; c0 < 256; c0 += 32) {
#pragma unroll
        for (int i = 0; i < 2; i++) {
            int idx = i * 256 + tid;
            int r = idx >> 3, c4 = (idx & 7) * 4;
            floatx4 v = *(const floatx4*)(X + (size_t)(row0 + r) * 256 + c0 + c4);
            bf16x4 vh, vl;
#pragma unroll
            for (int ii = 0; ii < 4; ii++) {
                bf16_t h, l; split_hl(v[ii], h, l);
                vh[ii] = h; vl[ii] = l;
            }
            *(bf16x4*)(&Xh[r * 40 + c4]) = vh;
            *(bf16x4*)(&Xl[r * 40 + c4]) = vl;
        }
#pragma unroll
        for (int i = 0; i < 4; i++) {
            int idx = i * 256 + tid;
            int d = idx >> 2, c8 = (idx & 3) * 8;
            *(bf16x8*)(&Wh[d * 40 + c8]) = *(const bf16x8*)(Wzh + d * 256 + c0 + c8);
            *(bf16x8*)(&Wl[d * 40 + c8]) = *(const bf16x8*)(Wzl + d * 256 + c0 + c8);
        }
        __syncthreads();
        bf16x8 ah = *(const bf16x8*)(&Xh[(w * 16 + m) * 40 + q * 8]);
        bf16x8 al = *(const bf16x8*)(&Xl[(w * 16 + m) * 40 + q * 8]);
#pragma unroll
        for (int nt = 0; nt < 16; nt++) {
            bf16x8 bh = *(const bf16x8*)(&Wh[(nt * 16 + m) * 40 + q * 8]);
            bf16x8 bl = *(const bf16x8*)(&Wl[(nt * 16 + m) * 40 + q * 8]);
            acc[nt] = __builtin_amdgcn_mfma_f32_16x16x32_bf16(ah, bh, acc[nt], 0, 0, 0);
            acc[nt] = __builtin_amdgcn_mfma_f32_16x16x32_bf16(ah, bl, acc[nt], 0, 0, 0);
            acc[nt] = __builtin_amdgcn_mfma_f32_16x16x32_bf16(al, bh, acc[nt], 0, 0, 0);
        }
        __syncthreads();
    }
    const int rbase = row0 + w * 16 + q * 4;
    if (z < 2) {
        bf16_t* Hhi = (z == 0) ? H1hi : H2hi;
        bf16_t* Hlo = (z == 0) ? H1lo : H2lo;
#pragma unroll
        for (int nt = 0; nt < 16; nt++)
#pragma unroll
            for (int r = 0; r < 4; r++) {
                bf16_t h, l; split_hl(acc[nt][r], h, l);
                int off = (rbase + r) * 256 + nt * 16 + m;
                Hhi[off] = h;
                Hlo[off] = l;
            }
    } else {
#pragma unroll
        for (int nt = 0; nt < 16; nt++)
#pragma unroll
            for (int r = 0; r < 4; r++) {
                int token = rbase + r;
                int b = token >> 11, n = token & 2047;
                H3t[(size_t)(b * 256 + nt * 16 + m) * 2048 + n] = (bf16_t)acc[nt][r];
            }
    }
}

// ---------------- kernel 3: flash attention, 512 threads = 8 waves = 128 queries ----------------
// Round-0 geometry (best measured global traffic: 143 MB, dur tracks hbm_bytes/1.2-1.5 TB/s)
// + round-3 aligned XOR-swizzled LDS (round-0 strides 520/80B split every odd-row b128)
// + bijective XCD chunk remap: the 16 q-blocks sharing one (b,kz) K/V chunk (1.5 MB)
//   land on one XCD -> chunk lives in its 4 MB L2 (2 chunks = 3 MB per XCD).
// Round-1 lesson: do NOT force min-waves (spill). Round-3 lesson: do NOT shrink blocks
// (doubles K/V re-reads).
#define KSW(row, byteoff) ((byteoff) ^ (((row) & 7) << 4))       // Kl: row stride 512B
#define VSW(row, byteoff) ((byteoff) ^ ((((row) >> 1) & 3) << 4)) // Vl/Pl: row stride 64B
__global__ __launch_bounds__(512, 2) void attn_kernel(
    const bf16_t* __restrict__ H1hi, const bf16_t* __restrict__ H1lo,
    const bf16_t* __restrict__ H2hi, const bf16_t* __restrict__ H2lo,
    const bf16_t* __restrict__ H3t, const unsigned* __restrict__ adjbits,
    float* __restrict__ Opart, float* __restrict__ mpart, float* __restrict__ lpart,
    int klen) {
    __shared__ bf16_t Kl[2][32 * 256];   // hi/lo K tile, swizzled (32 KB)
    __shared__ bf16_t Vl[256 * 32];      // Vt tile, swizzled (16 KB)
    __shared__ bf16_t Pl[8][16 * 32];    // per-wave P round-trip, swizzled (8 KB)

    // ---- XCD chunk remap (bijective, nwg % 8 == 0): HW round-robins linear wgid
    // across 8 XCDs; remap so each XCD gets contiguous nids = contiguous (b,kz) chunks.
    const int nwg = (int)(gridDim.x * gridDim.y * gridDim.z);       // 16*8*S
    const int wgid = (int)(blockIdx.x + (blockIdx.y << 4) + (blockIdx.z << 7));
    const int nid = (wgid & 7) * (nwg >> 3) + (wgid >> 3);
    const int qb = nid & 15;
    const int b  = (nid >> 4) & 7;
    const int kz = nid >> 7;

    const int q0 = qb * 128;
    const int tid = threadIdx.x;
    const int w = tid >> 6, lane = tid & 63;
    const int m = lane & 15, q = lane >> 4;

    char* KlB  = (char*)&Kl[0][0];
    char* KlB2 = (char*)&Kl[1][0];
    char* VlB  = (char*)&Vl[0];
    char* PlB  = (char*)&Pl[w][0];

    // Q fragments (A-layout: row = lane&15), hi+lo split, K=256 -> 8 chunks
    const bf16_t* qrh = H1hi + (size_t)(b * 2048 + q0 + w * 16 + m) * 256;
    const bf16_t* qrl = H1lo + (size_t)(b * 2048 + q0 + w * 16 + m) * 256;
    bf16x8 qhi[8], qlo[8];
#pragma unroll
    for (int ck = 0; ck < 8; ck++) {
        qhi[ck] = *(const bf16x8*)(qrh + ck * 32 + q * 8);
        qlo[ck] = *(const bf16x8*)(qrl + ck * 32 + q * 8);
    }

    bf16x8 vones;
#pragma unroll
    for (int i = 0; i < 8; i++) vones[i] = (bf16_t)1.0f;

    float m_run[4];
#pragma unroll
    for (int r = 0; r < 4; r++) m_run[r] = -3.0e38f;
    floatx4 l_acc = (floatx4){0.f, 0.f, 0.f, 0.f};
    floatx4 o[16];
#pragma unroll
    for (int i = 0; i < 16; i++) o[i] = (floatx4){0.f, 0.f, 0.f, 0.f};

    const unsigned* bitrow[4];
#pragma unroll
    for (int r = 0; r < 4; r++)
        bitrow[r] = adjbits + (size_t)(q0 + w * 16 + q * 4 + r) * 64;

    // staging: 1024 chunks of K (hi+lo) and 1024 of V across 512 threads -> 2 each
    bf16x8 rkh[2], rkl[2], rvv[2];
    const int kbeg = kz * klen, kend = kbeg + klen;

#pragma unroll
    for (int i = 0; i < 2; i++) {   // prefetch first tile
        int ci = i * 512 + tid;
        int kr = ci >> 5, c8 = (ci & 31) * 8;
        rkh[i] = *(const bf16x8*)(H2hi + (size_t)(b * 2048 + kbeg + kr) * 256 + c8);
        rkl[i] = *(const bf16x8*)(H2lo + (size_t)(b * 2048 + kbeg + kr) * 256 + c8);
        int d = ci >> 2, k8 = (ci & 3) * 8;
        rvv[i] = *(const bf16x8*)(H3t + (size_t)(b * 256 + d) * 2048 + kbeg + k8);
    }

    for (int k0 = kbeg; k0 < kend; k0 += 32) {
        __syncthreads();   // prior iter's LDS readers done
#pragma unroll
        for (int i = 0; i < 2; i++) {
            int ci = i * 512 + tid;
            int kr = ci >> 5, cb = (ci & 31) * 16;          // byte col
            *(bf16x8*)(KlB  + KSW(kr, kr * 512 + cb)) = rkh[i];
            *(bf16x8*)(KlB2 + KSW(kr, kr * 512 + cb)) = rkl[i];
            int d = ci >> 2, kb = (ci & 3) * 16;            // byte col
            *(bf16x8*)(VlB + VSW(d, d * 64 + kb)) = rvv[i];
        }
        __syncthreads();
        if (k0 + 32 < kend) {   // prefetch next tile while computing
            int kn = k0 + 32;
#pragma unroll
            for (int i = 0; i < 2; i++) {
                int ci = i * 512 + tid;
                int kr = ci >> 5, c8 = (ci & 31) * 8;
                rkh[i] = *(const bf16x8*)(H2hi + (size_t)(b * 2048 + kn + kr) * 256 + c8);
                rkl[i] = *(const bf16x8*)(H2lo + (size_t)(b * 2048 + kn + kr) * 256 + c8);
                int d = ci >> 2, k8 = (ci & 3) * 8;
                rvv[i] = *(const bf16x8*)(H3t + (size_t)(b * 256 + d) * 2048 + kn + k8);
            }
        }

        // ---- S = Q K^T (hi*hi + hi*lo + lo*hi), 16 rows x 32 keys per wave ----
        floatx4 s[2];
#pragma unroll
        for (int t = 0; t < 2; t++) {
            floatx4 accs = (floatx4){0.f, 0.f, 0.f, 0.f};
            const int row = t * 16 + m;
#pragma unroll
            for (int ck = 0; ck < 8; ck++) {
                const int cb = ck * 64 + q * 16;   // byte col
                bf16x8 khi = *(const bf16x8*)(KlB  + KSW(row, row * 512 + cb));
                bf16x8 klo = *(const bf16x8*)(KlB2 + KSW(row, row * 512 + cb));
                accs = __builtin_amdgcn_mfma_f32_16x16x32_bf16(qhi[ck], khi, accs, 0, 0, 0);
                accs = __builtin_amdgcn_mfma_f32_16x16x32_bf16(qhi[ck], klo, accs, 0, 0, 0);
                accs = __builtin_amdgcn_mfma_f32_16x16x32_bf16(qlo[ck], khi, accs, 0, 0, 0);
            }
            s[t] = accs;
        }

        // ---- leaky-relu + mask + tile row max ----
        unsigned aw[4];
#pragma unroll
        for (int r = 0; r < 4; r++) aw[r] = bitrow[r][k0 >> 5];
        float p[2][4], tmax[4];
#pragma unroll
        for (int r = 0; r < 4; r++) tmax[r] = -3.0e38f;
#pragma unroll
        for (int t = 0; t < 2; t++)
#pragma unroll
            for (int r = 0; r < 4; r++) {
                float v = s[t][r];
                v = (v > 0.f) ? v : 0.2f * v;
                v = ((aw[r] >> (t * 16 + m)) & 1u) ? v : -1.0e12f;
                p[t][r] = v;
                tmax[r] = fmaxf(tmax[r], v);
            }
#pragma unroll
        for (int off = 1; off < 16; off <<= 1)
#pragma unroll
            for (int r = 0; r < 4; r++)
                tmax[r] = fmaxf(tmax[r], __shfl_xor(tmax[r], off, 64));

        // ---- online softmax update (skip rescale when max didn't rise) ----
        int rise = 0;
        float mnew[4];
#pragma unroll
        for (int r = 0; r < 4; r++) {
            mnew[r] = fmaxf(m_run[r], tmax[r]);
            rise |= (mnew[r] > m_run[r]);
        }
        if (__any(rise)) {
#pragma unroll
            for (int r = 0; r < 4; r++) {
                float alpha = __expf(m_run[r] - mnew[r]);
                m_run[r] = mnew[r];
                l_acc[r] *= alpha;
#pragma unroll
                for (int nt = 0; nt < 16; nt++) o[nt][r] *= alpha;
            }
        }
#pragma unroll
        for (int t = 0; t < 2; t++)
#pragma unroll
            for (int r = 0; r < 4; r++)
                p[t][r] = __expf(p[t][r] - m_run[r]);

        // ---- P: C-layout -> per-wave LDS -> A-layout (no barrier; same wave) ----
#pragma unroll
        for (int t = 0; t < 2; t++)
#pragma unroll
            for (int r = 0; r < 4; r++) {
                int row = q * 4 + r;
                *(bf16_t*)(PlB + VSW(row, row * 64 + (t * 16 + m) * 2)) = (bf16_t)p[t][r];
            }
        bf16x8 pf = *(const bf16x8*)(PlB + VSW(m, m * 64 + q * 16));

        // ---- l += P @ ones (denominator as a 17th output column) ----
        l_acc = __builtin_amdgcn_mfma_f32_16x16x32_bf16(pf, vones, l_acc, 0, 0, 0);

        // ---- O += P @ V ----
#pragma unroll
        for (int nt = 0; nt < 16; nt++) {
            const int vr = nt * 16 + m;
            bf16x8 vf = *(const bf16x8*)(VlB + VSW(vr, vr * 64 + q * 16));
            o[nt] = __builtin_amdgcn_mfma_f32_16x16x32_bf16(pf, vf, o[nt], 0, 0, 0);
        }
    }

    // ---- epilogue: write unnormalized partials + per-row (m,l) ----
    const int rowg = kz * 16384 + b * 2048 + q0 + w * 16 + q * 4;
#pragma unroll
    for (int nt = 0; nt < 16; nt++)
#pragma unroll
        for (int r = 0; r < 4; r++)
            Opart[(size_t)(rowg + r) * 256 + nt * 16 + m] = o[nt][r];
    if (m == 0) {
#pragma unroll
        for (int r = 0; r < 4; r++) {
            mpart[rowg + r] = m_run[r];
            lpart[rowg + r] = l_acc[r];
        }
    }
}

// ---------------- kernel 4: merge splits + normalize + relu ----------------
__global__ __launch_bounds__(256) void merge_kernel(
    const float* __restrict__ Opart, const float* __restrict__ mpart,
    const float* __restrict__ lpart, float* __restrict__ out, int S) {
    int gid = blockIdx.x * 256 + threadIdx.x;
    int row = gid >> 6, c4 = (gid & 63) * 4;
    float M = -3.0e38f;
    for (int s = 0; s < S; s++) M = fmaxf(M, mpart[s * 16384 + row]);
    float denom = 0.f;
    float4 acc = make_float4(0.f, 0.f, 0.f, 0.f);
    for (int s = 0; s < S; s++) {
        float sc = __expf(mpart[s * 16384 + row] - M);
        denom += lpart[s * 16384 + row] * sc;
        float4 v = *(const float4*)(Opart + ((size_t)(s * 16384 + row)) * 256 + c4);
        acc.x += v.x * sc; acc.y += v.y * sc; acc.z += v.z * sc; acc.w += v.w * sc;
    }
    float inv = 1.f / denom;
    float4 r;
    r.x = fmaxf(acc.x * inv, 0.f);
    r.y = fmaxf(acc.y * inv, 0.f);
    r.z = fmaxf(acc.z * inv, 0.f);
    r.w = fmaxf(acc.w * inv, 0.f);
    *(float4*)(out + (size_t)row * 256 + c4) = r;
}

extern "C" void kernel_launch(void* const* d_in, const int* in_sizes, int n_in,
                              void* d_out, int out_size, void* d_ws, size_t ws_size,
                              hipStream_t stream) {
    const float* X   = (const float*)d_in[0];
    const int*   adj = (const int*)d_in[1];
    const float* W1  = (const float*)d_in[2];
    const float* W2  = (const float*)d_in[3];
    const float* W3  = (const float*)d_in[4];
    float* out = (float*)d_out;

    char* ws = (char*)d_ws;
    bf16_t* H1hi = (bf16_t*)(ws + (size_t)0 * S_H * 2);
    bf16_t* H1lo = (bf16_t*)(ws + (size_t)1 * S_H * 2);
    bf16_t* H2hi = (bf16_t*)(ws + (size_t)2 * S_H * 2);
    bf16_t* H2lo = (bf16_t*)(ws + (size_t)3 * S_H * 2);
    bf16_t* H3t  = (bf16_t*)(ws + (size_t)4 * S_H * 2);
    size_t off = (size_t)5 * S_H * 2;                    // 41,943,040
    bf16_t* Wthi = (bf16_t*)(ws + off);                  // 393,216 B
    bf16_t* Wtlo = (bf16_t*)(ws + off + 393216);         // 393,216 B
    float* mpart = (float*)(ws + off);                   // overlays Wt (dead after proj)
    float* lpart = (float*)(ws + off + 262144);
    unsigned* adjb = (unsigned*)(ws + off + 786432);     // 524,288 B
    size_t opart_off = off + 786432 + 524288;
    const size_t need2 = opart_off + (size_t)2 * 16384 * 256 * 4;  // ~76.8 MB

    int S = (ws_size >= need2) ? 2 : 1;
    float* Opart = (S > 1) ? (float*)(ws + opart_off) : out;

    adjbits_kernel<<<512, 256, 0, stream>>>(adj, adjb);
    wtrans_kernel<<<dim3(4, 4, 3), 256, 0, stream>>>(W1, W2, W3, Wthi, Wtlo);
    proj_kernel<<<dim3(256, 3), 256, 0, stream>>>(X, Wthi, Wtlo,
                                                  H1hi, H1lo, H2hi, H2lo, H3t);
    attn_kernel<<<dim3(16, 8, S), 512, 0, stream>>>(H1hi, H1lo, H2hi, H2lo, H3t,
                                                    adjb, Opart, mpart, lpart, 2048 / S);
    merge_kernel<<<4096, 256, 0, stream>>>(Opart, mpart, lpart, out, S);
}

// Round 5
// 237.954 us; speedup vs baseline: 1.8409x; 1.0291x over previous
//
#include <hip/hip_runtime.h>

typedef __bf16 bf16_t;
typedef __bf16 bf16x4 __attribute__((ext_vector_type(4)));
typedef __bf16 bf16x8 __attribute__((ext_vector_type(8)));
typedef float floatx4 __attribute__((ext_vector_type(4)));
typedef signed char i8_t;
typedef int intx4 __attribute__((ext_vector_type(4)));

__device__ inline void split_hl(float v, bf16_t& hi, bf16_t& lo) {
    hi = (bf16_t)v;
    lo = (bf16_t)(v - (float)hi);
}

// ---------------- kernel 0: adj int32 -> bitmask (2048 rows x 64 words) ----------------
__global__ void adjbits_kernel(const int* __restrict__ adj, unsigned* __restrict__ bits) {
    int id = blockIdx.x * 256 + threadIdx.x;   // 131072 words
    const int* p = adj + (size_t)id * 32;
    unsigned w = 0;
#pragma unroll
    for (int j = 0; j < 32; j += 4) {
        int4 v = *(const int4*)(p + j);
        w |= (v.x > 0 ? 1u : 0u) << j;
        w |= (v.y > 0 ? 1u : 0u) << (j + 1);
        w |= (v.z > 0 ? 1u : 0u) << (j + 2);
        w |= (v.w > 0 ? 1u : 0u) << (j + 3);
    }
    bits[id] = w;
}

// ---------------- kernel 1: transpose + hi/lo split W ----------------
__global__ void wtrans_kernel(const float* __restrict__ W1,
                              const float* __restrict__ W2,
                              const float* __restrict__ W3,
                              bf16_t* __restrict__ Wthi, bf16_t* __restrict__ Wtlo) {
    __shared__ float T[64 * 68];
    const int zi = blockIdx.z;
    const float* W = (zi == 0) ? W1 : ((zi == 1) ? W2 : W3);
    bf16_t* ohi = Wthi + zi * 256 * 256;
    bf16_t* olo = Wtlo + zi * 256 * 256;
    const int c0 = blockIdx.x * 64, d0 = blockIdx.y * 64;
    const int tid = threadIdx.x;
#pragma unroll
    for (int i = 0; i < 4; i++) {
        int idx = i * 256 + tid;
        int r = idx >> 4, c4 = (idx & 15) * 4;
        floatx4 v = *(const floatx4*)(W + (c0 + r) * 256 + d0 + c4);
        *(floatx4*)(&T[r * 68 + c4]) = v;
    }
    __syncthreads();
#pragma unroll
    for (int i = 0; i < 4; i++) {
        int idx = i * 256 + tid;
        int rd = idx & 63, cc4 = (idx >> 6) * 4;
        bf16x4 vh, vl;
#pragma unroll
        for (int ii = 0; ii < 4; ii++) {
            float v = T[(cc4 + ii) * 68 + rd];
            bf16_t h, l; split_hl(v, h, l);
            vh[ii] = h; vl[ii] = l;
        }
        *(bf16x4*)(ohi + (d0 + rd) * 256 + c0 + cc4) = vh;
        *(bf16x4*)(olo + (d0 + rd) * 256 + c0 + cc4) = vl;
    }
}

// ---------------- kernel 2: projections (X fp32, W hi/lo bf16) ----------------
// z=0 -> Q as i8 hi/lo + per-row scale sq; z=1 -> K as i8 hi/lo + sk; z=2 -> V^T bf16.
// i8 quantization: v ~= s*(qh*256+ql)/256, s = rowmax/127. 15-bit effective mantissa,
// comparable to the old bf16 hi/lo pair, but attn QK then runs at i8 K=64 MFMA rate
// with HALF the LDS bytes per FLOP (the round-4 diagnosis: attn is LDS-throughput-bound).
__global__ __launch_bounds__(256) void proj_kernel(
    const float* __restrict__ X,
    const bf16_t* __restrict__ Wthi, const bf16_t* __restrict__ Wtlo,
    i8_t* __restrict__ Q8h, i8_t* __restrict__ Q8l, float* __restrict__ sqv,
    i8_t* __restrict__ K8h, i8_t* __restrict__ K8l, float* __restrict__ skv,
    bf16_t* __restrict__ H3t) {
    __shared__ bf16_t Xh[64 * 40], Xl[64 * 40];
    __shared__ bf16_t Wh[256 * 40], Wl[256 * 40];
    const int z = blockIdx.y;
    const int row0 = blockIdx.x * 64;
    const int tid = threadIdx.x;
    const int w = tid >> 6, lane = tid & 63;
    const int m = lane & 15, q = lane >> 4;
    const bf16_t* Wzh = Wthi + z * 256 * 256;
    const bf16_t* Wzl = Wtlo + z * 256 * 256;

    floatx4 acc[16];
#pragma unroll
    for (int i = 0; i < 16; i++) acc[i] = (floatx4){0.f, 0.f, 0.f, 0.f};

    for (int c0 = 0; c0 < 256; c0 += 32) {
#pragma unroll
        for (int i = 0; i < 2; i++) {
            int idx = i * 256 + tid;
            int r = idx >> 3, c4 = (idx & 7) * 4;
            floatx4 v = *(const floatx4*)(X + (size_t)(row0 + r) * 256 + c0 + c4);
            bf16x4 vh, vl;
#pragma unroll
            for (int ii = 0; ii < 4; ii++) {
                bf16_t h, l; split_hl(v[ii], h, l);
                vh[ii] = h; vl[ii] = l;
            }
            *(bf16x4*)(&Xh[r * 40 + c4]) = vh;
            *(bf16x4*)(&Xl[r * 40 + c4]) = vl;
        }
#pragma unroll
        for (int i = 0; i < 4; i++) {
            int idx = i * 256 + tid;
            int d = idx >> 2, c8 = (idx & 3) * 8;
            *(bf16x8*)(&Wh[d * 40 + c8]) = *(const bf16x8*)(Wzh + d * 256 + c0 + c8);
            *(bf16x8*)(&Wl[d * 40 + c8]) = *(const bf16x8*)(Wzl + d * 256 + c0 + c8);
        }
        __syncthreads();
        bf16x8 ah = *(const bf16x8*)(&Xh[(w * 16 + m) * 40 + q * 8]);
        bf16x8 al = *(const bf16x8*)(&Xl[(w * 16 + m) * 40 + q * 8]);
#pragma unroll
        for (int nt = 0; nt < 16; nt++) {
            bf16x8 bh = *(const bf16x8*)(&Wh[(nt * 16 + m) * 40 + q * 8]);
            bf16x8 bl = *(const bf16x8*)(&Wl[(nt * 16 + m) * 40 + q * 8]);
            acc[nt] = __builtin_amdgcn_mfma_f32_16x16x32_bf16(ah, bh, acc[nt], 0, 0, 0);
            acc[nt] = __builtin_amdgcn_mfma_f32_16x16x32_bf16(ah, bl, acc[nt], 0, 0, 0);
            acc[nt] = __builtin_amdgcn_mfma_f32_16x16x32_bf16(al, bh, acc[nt], 0, 0, 0);
        }
        __syncthreads();
    }
    const int rbase = row0 + w * 16 + q * 4;
    if (z < 2) {
        i8_t* Dh = (z == 0) ? Q8h : K8h;
        i8_t* Dl = (z == 0) ? Q8l : K8l;
        float* sv = (z == 0) ? sqv : skv;
        // per-row absmax: local over nt, then across the 16 m-lanes of this row
        float am[4] = {0.f, 0.f, 0.f, 0.f};
#pragma unroll
        for (int nt = 0; nt < 16; nt++)
#pragma unroll
            for (int r = 0; r < 4; r++) am[r] = fmaxf(am[r], fabsf(acc[nt][r]));
#pragma unroll
        for (int off = 1; off < 16; off <<= 1)
#pragma unroll
            for (int r = 0; r < 4; r++)
                am[r] = fmaxf(am[r], __shfl_xor(am[r], off, 64));
        float sc[4], inv[4];
#pragma unroll
        for (int r = 0; r < 4; r++) {
            sc[r]  = (am[r] > 0.f) ? am[r] * (1.f / 127.f) : 1.f;
            inv[r] = (am[r] > 0.f) ? 127.f / am[r] : 0.f;
        }
#pragma unroll
        for (int nt = 0; nt < 16; nt++)
#pragma unroll
            for (int r = 0; r < 4; r++) {
                float vq = acc[nt][r] * inv[r];
                float qh = rintf(vq);
                float ql = fminf(fmaxf(rintf((vq - qh) * 256.f), -127.f), 127.f);
                int offo = (rbase + r) * 256 + nt * 16 + m;
                Dh[offo] = (i8_t)(int)qh;
                Dl[offo] = (i8_t)(int)ql;
            }
        if (m == 0) {
#pragma unroll
            for (int r = 0; r < 4; r++) sv[rbase + r] = sc[r];
        }
    } else {
#pragma unroll
        for (int nt = 0; nt < 16; nt++)
#pragma unroll
            for (int r = 0; r < 4; r++) {
                int token = rbase + r;
                int b = token >> 11, n = token & 2047;
                H3t[(size_t)(b * 256 + nt * 16 + m) * 2048 + n] = (bf16_t)acc[nt][r];
            }
    }
}

// ---------------- kernel 3: flash attention ----------------
// 256 threads = 4 waves = 64 queries; grid (32,8,2) = 512 blocks, XCD chunk remap
// (round-4 verified: FETCH 30 MB, K/V stream L2-resident -> 64-q blocks are now safe).
// QK^T in int8 hi/lo via mfma_i32_16x16x64_i8: K LDS reads/wave/tile 32 -> 16,
// QK MFMA cycles ~halved. S = sq*sk*(hh + m/256), exact i32 accumulation, ql*kl dropped
// (score error sigma ~2e-3, negligible vs 0.031 absmax budget). PV stays bf16.
// Round-1 lesson: never force min-waves high (spill). Round-4 lesson: LDS-instr bound.
#define K8SW(row, off) ((off) ^ (((row) & 7) << 4))        // K8 row stride 256B
#define VSW(row, off)  ((off) ^ ((((row) >> 1) & 3) << 4)) // Vl/Pl row stride 64B
__global__ __launch_bounds__(256, 2) void attn_kernel(
    const i8_t* __restrict__ Q8h, const i8_t* __restrict__ Q8l,
    const float* __restrict__ sqv,
    const i8_t* __restrict__ K8h, const i8_t* __restrict__ K8l,
    const float* __restrict__ skv,
    const bf16_t* __restrict__ H3t, const unsigned* __restrict__ adjbits,
    float* __restrict__ Opart, float* __restrict__ mpart, float* __restrict__ lpart,
    int klen) {
    __shared__ i8_t K8[2][32 * 256];    // hi/lo K tile, swizzled (16 KB)
    __shared__ bf16_t Vl[256 * 32];     // Vt tile, swizzled (16 KB)
    __shared__ bf16_t Pl[4][16 * 32];   // per-wave P round-trip (4 KB)

    // XCD chunk remap (bijective, nwg % 8 == 0): each XCD gets contiguous nids
    // = contiguous (b,kz) K/V chunks (~1 MB each, fits 4 MB XCD L2).
    const int nwg = (int)(gridDim.x * gridDim.y * gridDim.z);   // 32*8*S
    const int wgid = (int)(blockIdx.x + (blockIdx.y << 5) + (blockIdx.z << 8));
    const int nid = (wgid & 7) * (nwg >> 3) + (wgid >> 3);
    const int qb = nid & 31;
    const int b  = (nid >> 5) & 7;
    const int kz = nid >> 8;

    const int q0 = qb * 64;
    const int tid = threadIdx.x;
    const int w = tid >> 6, lane = tid & 63;
    const int m = lane & 15, q = lane >> 4;

    char* K8B0 = (char*)&K8[0][0];
    char* K8B1 = (char*)&K8[1][0];
    char* VlB  = (char*)&Vl[0];
    char* PlB  = (char*)&Pl[w][0];

    // Q fragments (A-layout row = lane&15), i8 hi/lo, K=256 -> 4 chunks of 64
    const i8_t* qrh = Q8h + (size_t)(b * 2048 + q0 + w * 16 + m) * 256;
    const i8_t* qrl = Q8l + (size_t)(b * 2048 + q0 + w * 16 + m) * 256;
    intx4 qh8[4], ql8[4];
#pragma unroll
    for (int ck = 0; ck < 4; ck++) {
        qh8[ck] = *(const intx4*)(qrh + ck * 64 + q * 16);
        ql8[ck] = *(const intx4*)(qrl + ck * 64 + q * 16);
    }
    float sq4[4];
#pragma unroll
    for (int r = 0; r < 4; r++) sq4[r] = sqv[b * 2048 + q0 + w * 16 + q * 4 + r];

    bf16x8 vones;
#pragma unroll
    for (int i = 0; i < 8; i++) vones[i] = (bf16_t)1.0f;

    float m_run[4];
#pragma unroll
    for (int r = 0; r < 4; r++) m_run[r] = -3.0e38f;
    floatx4 l_acc = (floatx4){0.f, 0.f, 0.f, 0.f};
    floatx4 o[16];
#pragma unroll
    for (int i = 0; i < 16; i++) o[i] = (floatx4){0.f, 0.f, 0.f, 0.f};

    const unsigned* bitrow[4];
#pragma unroll
    for (int r = 0; r < 4; r++)
        bitrow[r] = adjbits + (size_t)(q0 + w * 16 + q * 4 + r) * 64;

    // staging (register-prefetched, proven structure): K8 512 chunks, V 1024 chunks
    intx4 rkh[2], rkl[2];
    bf16x8 rvv[4];
    float skt[2], skn[2];
    const int kbeg = kz * klen, kend = kbeg + klen;

#pragma unroll
    for (int i = 0; i < 2; i++) {   // prefetch first tile: K
        int ci = i * 256 + tid;
        int kr = ci >> 4, cb = (ci & 15) * 16;
        rkh[i] = *(const intx4*)(K8h + (size_t)(b * 2048 + kbeg + kr) * 256 + cb);
        rkl[i] = *(const intx4*)(K8l + (size_t)(b * 2048 + kbeg + kr) * 256 + cb);
    }
#pragma unroll
    for (int i = 0; i < 4; i++) {   // prefetch first tile: V
        int ci = i * 256 + tid;
        int d = ci >> 2, k8 = (ci & 3) * 8;
        rvv[i] = *(const bf16x8*)(H3t + (size_t)(b * 256 + d) * 2048 + kbeg + k8);
    }
    skt[0] = skv[b * 2048 + kbeg + m];
    skt[1] = skv[b * 2048 + kbeg + 16 + m];

    for (int k0 = kbeg; k0 < kend; k0 += 32) {
        __syncthreads();   // prior iter's LDS readers done
#pragma unroll
        for (int i = 0; i < 2; i++) {
            int ci = i * 256 + tid;
            int kr = ci >> 4, cb = (ci & 15) * 16;
            *(intx4*)(K8B0 + K8SW(kr, kr * 256 + cb)) = rkh[i];
            *(intx4*)(K8B1 + K8SW(kr, kr * 256 + cb)) = rkl[i];
        }
#pragma unroll
        for (int i = 0; i < 4; i++) {
            int ci = i * 256 + tid;
            int d = ci >> 2, kb = (ci & 3) * 16;
            *(bf16x8*)(VlB + VSW(d, d * 64 + kb)) = rvv[i];
        }
        __syncthreads();
        if (k0 + 32 < kend) {   // prefetch next tile while computing
            int kn = k0 + 32;
#pragma unroll
            for (int i = 0; i < 2; i++) {
                int ci = i * 256 + tid;
                int kr = ci >> 4, cb = (ci & 15) * 16;
                rkh[i] = *(const intx4*)(K8h + (size_t)(b * 2048 + kn + kr) * 256 + cb);
                rkl[i] = *(const intx4*)(K8l + (size_t)(b * 2048 + kn + kr) * 256 + cb);
            }
#pragma unroll
            for (int i = 0; i < 4; i++) {
                int ci = i * 256 + tid;
                int d = ci >> 2, k8 = (ci & 3) * 8;
                rvv[i] = *(const bf16x8*)(H3t + (size_t)(b * 256 + d) * 2048 + kn + k8);
            }
            skn[0] = skv[b * 2048 + kn + m];
            skn[1] = skv[b * 2048 + kn + 16 + m];
        }

        // ---- S = Q K^T in i8 hi/lo: hh + (qh*kl + ql*kh)/256, scaled ----
        float s[2][4];
#pragma unroll
        for (int t = 0; t < 2; t++) {
            intx4 ch = {0, 0, 0, 0}, cm = {0, 0, 0, 0};
            const int row = t * 16 + m;
#pragma unroll
            for (int ck = 0; ck < 4; ck++) {
                const int cb2 = ck * 64 + q * 16;
                intx4 kh = *(const intx4*)(K8B0 + K8SW(row, row * 256 + cb2));
                intx4 kl = *(const intx4*)(K8B1 + K8SW(row, row * 256 + cb2));
                ch = __builtin_amdgcn_mfma_i32_16x16x64_i8(qh8[ck], kh, ch, 0, 0, 0);
                cm = __builtin_amdgcn_mfma_i32_16x16x64_i8(qh8[ck], kl, cm, 0, 0, 0);
                cm = __builtin_amdgcn_mfma_i32_16x16x64_i8(ql8[ck], kh, cm, 0, 0, 0);
            }
#pragma unroll
            for (int r = 0; r < 4; r++)
                s[t][r] = fmaf((float)cm[r], 0.00390625f, (float)ch[r]) * (sq4[r] * skt[t]);
        }

        // ---- leaky-relu + mask + tile row max ----
        unsigned aw[4];
#pragma unroll
        for (int r = 0; r < 4; r++) aw[r] = bitrow[r][k0 >> 5];
        float p[2][4], tmax[4];
#pragma unroll
        for (int r = 0; r < 4; r++) tmax[r] = -3.0e38f;
#pragma unroll
        for (int t = 0; t < 2; t++)
#pragma unroll
            for (int r = 0; r < 4; r++) {
                float v = s[t][r];
                v = (v > 0.f) ? v : 0.2f * v;
                v = ((aw[r] >> (t * 16 + m)) & 1u) ? v : -1.0e12f;
                p[t][r] = v;
                tmax[r] = fmaxf(tmax[r], v);
            }
#pragma unroll
        for (int off = 1; off < 16; off <<= 1)
#pragma unroll
            for (int r = 0; r < 4; r++)
                tmax[r] = fmaxf(tmax[r], __shfl_xor(tmax[r], off, 64));

        // ---- online softmax update (skip rescale when max didn't rise) ----
        int rise = 0;
        float mnew[4];
#pragma unroll
        for (int r = 0; r < 4; r++) {
            mnew[r] = fmaxf(m_run[r], tmax[r]);
            rise |= (mnew[r] > m_run[r]);
        }
        if (__any(rise)) {
#pragma unroll
            for (int r = 0; r < 4; r++) {
                float alpha = __expf(m_run[r] - mnew[r]);
                m_run[r] = mnew[r];
                l_acc[r] *= alpha;
#pragma unroll
                for (int nt = 0; nt < 16; nt++) o[nt][r] *= alpha;
            }
        }
#pragma unroll
        for (int t = 0; t < 2; t++)
#pragma unroll
            for (int r = 0; r < 4; r++)
                p[t][r] = __expf(p[t][r] - m_run[r]);

        // ---- P: C-layout -> per-wave LDS -> A-layout (no barrier; same wave) ----
#pragma unroll
        for (int t = 0; t < 2; t++)
#pragma unroll
            for (int r = 0; r < 4; r++) {
                int row = q * 4 + r;
                *(bf16_t*)(PlB + VSW(row, row * 64 + (t * 16 + m) * 2)) = (bf16_t)p[t][r];
            }
        bf16x8 pf = *(const bf16x8*)(PlB + VSW(m, m * 64 + q * 16));

        // ---- l += P @ ones (denominator as a 17th output column) ----
        l_acc = __builtin_amdgcn_mfma_f32_16x16x32_bf16(pf, vones, l_acc, 0, 0, 0);

        // ---- O += P @ V ----
#pragma unroll
        for (int nt = 0; nt < 16; nt++) {
            const int vr = nt * 16 + m;
            bf16x8 vf = *(const bf16x8*)(VlB + VSW(vr, vr * 64 + q * 16));
            o[nt] = __builtin_amdgcn_mfma_f32_16x16x32_bf16(pf, vf, o[nt], 0, 0, 0);
        }
        skt[0] = skn[0];
        skt[1] = skn[1];
    }

    // ---- epilogue: write unnormalized partials + per-row (m,l) ----
    const int rowg = kz * 16384 + b * 2048 + q0 + w * 16 + q * 4;
#pragma unroll
    for (int nt = 0; nt < 16; nt++)
#pragma unroll
        for (int r = 0; r < 4; r++)
            Opart[(size_t)(rowg + r) * 256 + nt * 16 + m] = o[nt][r];
    if (m == 0) {
#pragma unroll
        for (int r = 0; r < 4; r++) {
            mpart[rowg + r] = m_run[r];
            lpart[rowg + r] = l_acc[r];
        }
    }
}

// ---------------- kernel 4: merge splits + normalize + relu ----------------
__global__ __launch_bounds__(256) void merge_kernel(
    const float* __restrict__ Opart, const float* __restrict__ mpart,
    const float* __restrict__ lpart, float* __restrict__ out, int S) {
    int gid = blockIdx.x * 256 + threadIdx.x;
    int row = gid >> 6, c4 = (gid & 63) * 4;
    float M = -3.0e38f;
    for (int s = 0; s < S; s++) M = fmaxf(M, mpart[s * 16384 + row]);
    float denom = 0.f;
    float4 acc = make_float4(0.f, 0.f, 0.f, 0.f);
    for (int s = 0; s < S; s++) {
        float sc = __expf(mpart[s * 16384 + row] - M);
        denom += lpart[s * 16384 + row] * sc;
        float4 v = *(const float4*)(Opart + ((size_t)(s * 16384 + row)) * 256 + c4);
        acc.x += v.x * sc; acc.y += v.y * sc; acc.z += v.z * sc; acc.w += v.w * sc;
    }
    float inv = 1.f / denom;
    float4 r;
    r.x = fmaxf(acc.x * inv, 0.f);
    r.y = fmaxf(acc.y * inv, 0.f);
    r.z = fmaxf(acc.z * inv, 0.f);
    r.w = fmaxf(acc.w * inv, 0.f);
    *(float4*)(out + (size_t)row * 256 + c4) = r;
}

extern "C" void kernel_launch(void* const* d_in, const int* in_sizes, int n_in,
                              void* d_out, int out_size, void* d_ws, size_t ws_size,
                              hipStream_t stream) {
    const float* X   = (const float*)d_in[0];
    const int*   adj = (const int*)d_in[1];
    const float* W1  = (const float*)d_in[2];
    const float* W2  = (const float*)d_in[3];
    const float* W3  = (const float*)d_in[4];
    float* out = (float*)d_out;

    char* ws = (char*)d_ws;
    i8_t* Q8h = (i8_t*)(ws + ((size_t)0 << 20));    // 16384*256 = 4 MB each
    i8_t* Q8l = (i8_t*)(ws + ((size_t)4 << 20));
    i8_t* K8h = (i8_t*)(ws + ((size_t)8 << 20));
    i8_t* K8l = (i8_t*)(ws + ((size_t)12 << 20));
    bf16_t* H3t = (bf16_t*)(ws + ((size_t)16 << 20));   // 8 MB
    float* sqv = (float*)(ws + ((size_t)24 << 20));     // 64 KB
    float* skv = (float*)(ws + ((size_t)24 << 20) + 65536);
    size_t wt0 = ((size_t)24 << 20) + 131072;
    bf16_t* Wthi = (bf16_t*)(ws + wt0);                 // 393,216 B
    bf16_t* Wtlo = (bf16_t*)(ws + wt0 + 393216);        // 393,216 B
    float* mpart = (float*)(ws + wt0);                  // overlays Wt (dead after proj)
    float* lpart = (float*)(ws + wt0 + 131072);
    unsigned* adjb = (unsigned*)(ws + wt0 + 786432);    // 524,288 B
    size_t opart_off = wt0 + 786432 + 524288;
    const size_t need2 = opart_off + (size_t)2 * 16384 * 256 * 4;  // ~57.4 MB

    int S = (ws_size >= need2) ? 2 : 1;
    float* Opart = (S > 1) ? (float*)(ws + opart_off) : out;

    adjbits_kernel<<<512, 256, 0, stream>>>(adj, adjb);
    wtrans_kernel<<<dim3(4, 4, 3), 256, 0, stream>>>(W1, W2, W3, Wthi, Wtlo);
    proj_kernel<<<dim3(256, 3), 256, 0, stream>>>(X, Wthi, Wtlo,
                                                  Q8h, Q8l, sqv, K8h, K8l, skv, H3t);
    attn_kernel<<<dim3(32, 8, S), 256, 0, stream>>>(Q8h, Q8l, sqv, K8h, K8l, skv,
                                                    H3t, adjb, Opart, mpart, lpart,
                                                    2048 / S);
    merge_kernel<<<4096, 256, 0, stream>>>(Opart, mpart, lpart, out, S);
}